// Round 3
// baseline (634.543 us; speedup 1.0000x reference)
//
#include <hip/hip_runtime.h>

#define B_ROWS 8192
#define IN_DIM 2048
#define H_DIM  2048
#define K_DIM  4096              // IN + H
#define CH_OFF (B_ROWS * H_DIM)  // offset of h_t in d_out
#define NT     (K_DIM / 32)      // 128 K-tiles of depth 32

typedef __attribute__((ext_vector_type(8))) short bf16x8;
typedef __attribute__((ext_vector_type(8))) short short8;
typedef __attribute__((ext_vector_type(4))) float f32x4;

// fp32 -> bf16 round-to-nearest-even
static __device__ __forceinline__ unsigned short f2bf(float f) {
  union { float f; unsigned u; } v; v.f = f;
  unsigned r = v.u + 0x7fffu + ((v.u >> 16) & 1u);
  return (unsigned short)(r >> 16);
}

// async 16B global -> LDS (wave-uniform base + lane*16 on the LDS side)
static __device__ __forceinline__ void load_lds16(const void* g, void* l) {
  __builtin_amdgcn_global_load_lds(
      (const __attribute__((address_space(1))) unsigned int*)(unsigned long long)(uintptr_t)g,
      (__attribute__((address_space(3))) unsigned int*)(unsigned int)(uintptr_t)l,
      16, 0, 0);
}

// ---------------------------------------------------------------------------
// Pack [input | hidden] (fp32) -> A bf16 [8192][4096]
// ---------------------------------------------------------------------------
__global__ __launch_bounds__(256) void pack_act(
    const float* __restrict__ inp, const float* __restrict__ hid,
    short* __restrict__ out) {
  int idx = blockIdx.x * 256 + threadIdx.x;
  int m = idx >> 9;
  int k = (idx & 511) * 8;
  const float* s = (k < IN_DIM) ? (inp + m * IN_DIM + k)
                                : (hid + m * H_DIM + (k - IN_DIM));
  float4 a = *(const float4*)s;
  float4 c = *(const float4*)(s + 4);
  short8 o;
  o[0] = (short)f2bf(a.x); o[1] = (short)f2bf(a.y);
  o[2] = (short)f2bf(a.z); o[3] = (short)f2bf(a.w);
  o[4] = (short)f2bf(c.x); o[5] = (short)f2bf(c.y);
  o[6] = (short)f2bf(c.z); o[7] = (short)f2bf(c.w);
  *(short8*)(out + (size_t)idx * 8) = o;
}

// ---------------------------------------------------------------------------
// Pack + transpose weights -> WT[n][k] bf16, n = (h>>4)*64 + gate*16 + (h&15)
// ---------------------------------------------------------------------------
__global__ __launch_bounds__(256) void pack_w(
    const float* __restrict__ wi0, const float* __restrict__ wi1,
    const float* __restrict__ wi2, const float* __restrict__ wi3,
    const float* __restrict__ wh0, const float* __restrict__ wh1,
    const float* __restrict__ wh2, const float* __restrict__ wh3,
    short* __restrict__ out) {
  __shared__ float tileS[64][65];
  int b = blockIdx.x;
  int w = b >> 10;
  int tile = b & 1023;
  int tk = tile >> 5;
  int th = tile & 31;
  const float* src;
  switch (w) {
    case 0: src = wi0; break; case 1: src = wi1; break;
    case 2: src = wi2; break; case 3: src = wi3; break;
    case 4: src = wh0; break; case 5: src = wh1; break;
    case 6: src = wh2; break; default: src = wh3; break;
  }
  int g = w & 3, half = w >> 2;
  int t = threadIdx.x;
  #pragma unroll
  for (int it = 0; it < 4; ++it) {
    int idx = it * 256 + t;
    int sr = idx >> 4, sc = idx & 15;
    float4 v = *(const float4*)(src + (tk * 64 + sr) * H_DIM + th * 64 + sc * 4);
    tileS[sr][sc * 4 + 0] = v.x; tileS[sr][sc * 4 + 1] = v.y;
    tileS[sr][sc * 4 + 2] = v.z; tileS[sr][sc * 4 + 3] = v.w;
  }
  __syncthreads();
  #pragma unroll
  for (int it = 0; it < 2; ++it) {
    int idx = it * 256 + t;
    int orow = idx >> 3;
    int okg = idx & 7;
    short8 o;
    #pragma unroll
    for (int j = 0; j < 8; ++j) o[j] = (short)f2bf(tileS[okg * 8 + j][orow]);
    int hg = th * 64 + orow;
    int n = (hg >> 4) * 64 + g * 16 + (hg & 15);
    int off = n * K_DIM + half * IN_DIM + tk * 64 + okg * 8;
    *(short8*)(out + off) = o;
  }
}

// ---------------------------------------------------------------------------
// Fused GEMM (bf16 MFMA) + LSTM epilogue.
// 256x256 tile, BK=32, 4-slot LDS rotation, counted vmcnt(8),
// one-phase-ahead register prefetch (counted lgkmcnt), 2 barriers/K-tile.
// ---------------------------------------------------------------------------
__global__ __launch_bounds__(512, 2) void lstm_gemm(
    const short* __restrict__ actB,   // [8192][4096] bf16
    const short* __restrict__ wB,     // [8192][4096] bf16 packed W^T
    const float* __restrict__ cprev,
    const float* __restrict__ bi_p, const float* __restrict__ bf_p,
    const float* __restrict__ bg_p, const float* __restrict__ bo_p,
    float* __restrict__ out) {
  __shared__ __align__(16) short As[4][8192];   // 64 KB (4 slots x 16 KB)
  __shared__ __align__(16) short Bs[4][8192];   // 64 KB

  int bid = blockIdx.x;
  int swz = (bid & 7) * 128 + (bid >> 3);   // bijective XCD swizzle (1024%8==0)
  int mblk = swz >> 5, nblk = swz & 31;
  int m0 = mblk * 256;
  int n0 = nblk * 256;

  int t = threadIdx.x;
  int lane = t & 63, wid = t >> 6;
  int wm = wid >> 2, wn = wid & 3;          // 2M x 4N wave grid
  int q = lane >> 4, cl = lane & 15;

  // --- staging: per thread 2 A-chunks + 2 B-chunks per K-tile (16B each) ---
  const short* aS[2]; const short* bS[2];
  char* aD[2]; char* bD[2];
  #pragma unroll
  for (int it = 0; it < 2; ++it) {
    int idx = it * 512 + t;
    int rp = idx >> 3, c = idx & 7;
    int cu = c ^ (rp & 7);                  // logical chunk at this physical pos
    int half = cu >> 2, qq = cu & 3;
    aS[it] = actB + (size_t)(m0 + half * 128 + rp) * K_DIM + qq * 8;
    bS[it] = wB   + (size_t)(n0 + half * 128 + rp) * K_DIM + qq * 8;
    aD[it] = (char*)&As[0][0] + idx * 16;
    bD[it] = (char*)&Bs[0][0] + idx * 16;
  }
  auto stageA = [&](int kt) {
    int so = (kt & 3) * 16384, ko = kt * 32;
    load_lds16(aS[0] + ko, aD[0] + so);
    load_lds16(aS[1] + ko, aD[1] + so);
  };
  auto stageB = [&](int kt) {
    int so = (kt & 3) * 16384, ko = kt * 32;
    load_lds16(bS[0] + ko, bD[0] + so);
    load_lds16(bS[1] + ko, bD[1] + so);
  };
  // --- fragment reads (swizzled) ---
  auto ldA = [&](int sl, int rp, int cu) -> bf16x8 {
    int ch = cu ^ (rp & 7);
    return *(const bf16x8*)((const char*)&As[sl][0] + rp * 128 + ch * 16);
  };
  auto ldB = [&](int sl, int rp, int cu) -> bf16x8 {
    int ch = cu ^ (rp & 7);
    return *(const bf16x8*)((const char*)&Bs[sl][0] + rp * 128 + ch * 16);
  };

  f32x4 zero = {0.f, 0.f, 0.f, 0.f};
  f32x4 acc[8][4];
  #pragma unroll
  for (int mi = 0; mi < 8; ++mi)
    #pragma unroll
    for (int ni = 0; ni < 4; ++ni) acc[mi][ni] = zero;

  int cuA = wm * 4 + q;
  int cuB = (wn >> 1) * 4 + q;
  int nb = (wn & 1) * 64;

  // prologue: 3 tiles in flight; tile 0 published; preload tile-0 frags
  stageA(0); stageB(0); stageA(1); stageB(1); stageA(2); stageB(2);
  asm volatile("s_waitcnt vmcnt(8)" ::: "memory");   // tile 0 landed
  asm volatile("s_barrier" ::: "memory");

  bf16x8 aP[4], bP[4], aQ[4], bQ[4];
  #pragma unroll
  for (int i = 0; i < 4; ++i) {
    aP[i] = ldA(0, i * 16 + cl, cuA);
    bP[i] = ldB(0, nb + i * 16 + cl, cuB);
  }

  // one iteration: consumes (aC,bC) for P1, prefetches into (aN2,bN2)
  auto iter = [&](int kt, bf16x8 (&aC)[4], bf16x8 (&bC)[4],
                  bf16x8 (&aN2)[4], bf16x8 (&bN2)[4]) {
    int sl = kt & 3, sl1 = (kt + 1) & 3;
    bf16x8 aH[4];
    // ---- P1: prefetch this tile's hi-half A frags, then MFMA lo-half ----
    #pragma unroll
    for (int i = 0; i < 4; ++i) aH[i] = ldA(sl, (i + 4) * 16 + cl, cuA);
    if (kt + 3 < NT) stageA(kt + 3);
    __builtin_amdgcn_sched_barrier(0);
    __builtin_amdgcn_s_setprio(1);
    #pragma unroll
    for (int mi = 0; mi < 4; ++mi)
      #pragma unroll
      for (int ni = 0; ni < 4; ++ni)
        acc[mi][ni] = __builtin_amdgcn_mfma_f32_16x16x32_bf16(
            aC[mi], bC[ni], acc[mi][ni], 0, 0, 0);
    __builtin_amdgcn_s_setprio(0);
    __builtin_amdgcn_sched_barrier(0);
    // ---- P2: publish tile kt+1, prefetch its frags, MFMA hi-half ----
    if (kt + 3 < NT) {
      stageB(kt + 3);
      asm volatile("s_waitcnt vmcnt(8)" ::: "memory");   // tile kt+1 landed
    } else if (kt + 3 == NT) {
      asm volatile("s_waitcnt vmcnt(4)" ::: "memory");
    } else if (kt + 2 == NT) {
      asm volatile("s_waitcnt vmcnt(0)" ::: "memory");
    }
    asm volatile("s_barrier" ::: "memory");              // tile kt+1 readable
    if (kt + 1 < NT) {
      #pragma unroll
      for (int i = 0; i < 4; ++i) {
        aN2[i] = ldA(sl1, i * 16 + cl, cuA);
        bN2[i] = ldB(sl1, nb + i * 16 + cl, cuB);
      }
    }
    __builtin_amdgcn_sched_barrier(0);
    __builtin_amdgcn_s_setprio(1);
    #pragma unroll
    for (int mi = 0; mi < 4; ++mi)
      #pragma unroll
      for (int ni = 0; ni < 4; ++ni)
        acc[mi + 4][ni] = __builtin_amdgcn_mfma_f32_16x16x32_bf16(
            aH[mi], bC[ni], acc[mi + 4][ni], 0, 0, 0);
    __builtin_amdgcn_s_setprio(0);
    __builtin_amdgcn_sched_barrier(0);
    asm volatile("s_barrier" ::: "memory");              // slot-reuse fence
  };

  #pragma unroll 1
  for (int kt = 0; kt < NT; kt += 2) {
    iter(kt,     aP, bP, aQ, bQ);
    iter(kt + 1, aQ, bQ, aP, bP);
  }

  // ---- epilogue: each lane holds i,f,g,o for the same (row, h) ----
  int hg = (nblk * 4 + wn) * 16 + cl;
  float vbi = bi_p[hg], vbf = bf_p[hg], vbg = bg_p[hg], vbo = bo_p[hg];
  int mbase = m0 + wm * 128;
  #pragma unroll
  for (int mi = 0; mi < 8; ++mi) {
    #pragma unroll
    for (int r = 0; r < 4; ++r) {
      int mg = mbase + mi * 16 + q * 4 + r;
      float pi = acc[mi][0][r] + vbi;
      float pf = acc[mi][1][r] + vbf;
      float pg = acc[mi][2][r] + vbg;
      float po = acc[mi][3][r] + vbo;
      float iv = 1.f / (1.f + __expf(-pi));
      float fv = 1.f / (1.f + __expf(-pf));
      float gv = 1.f - 2.f / (__expf(2.f * pg) + 1.f);
      float ov = 1.f / (1.f + __expf(-po));
      float cp = cprev[(size_t)mg * H_DIM + hg];
      float cv = fv * cp + iv * gv;
      float tc = 1.f - 2.f / (__expf(2.f * cv) + 1.f);
      out[(size_t)mg * H_DIM + hg] = cv;
      out[CH_OFF + (size_t)mg * H_DIM + hg] = ov * tc;
    }
  }
}

extern "C" void kernel_launch(void* const* d_in, const int* in_sizes, int n_in,
                              void* d_out, int out_size, void* d_ws, size_t ws_size,
                              hipStream_t stream) {
  const float* inp   = (const float*)d_in[0];
  const float* hid   = (const float*)d_in[1];
  const float* cprev = (const float*)d_in[2];
  short* actB = (short*)d_ws;
  short* wB   = actB + (size_t)B_ROWS * K_DIM;

  pack_act<<<dim3(B_ROWS * K_DIM / 8 / 256), dim3(256), 0, stream>>>(inp, hid, actB);
  pack_w<<<dim3(8 * 1024), dim3(256), 0, stream>>>(
      (const float*)d_in[3], (const float*)d_in[4],
      (const float*)d_in[5], (const float*)d_in[6],
      (const float*)d_in[7], (const float*)d_in[8],
      (const float*)d_in[9], (const float*)d_in[10], wB);
  lstm_gemm<<<dim3(1024), dim3(512), 0, stream>>>(
      actB, wB, cprev,
      (const float*)d_in[11], (const float*)d_in[12],
      (const float*)d_in[13], (const float*)d_in[14],
      (float*)d_out);
}